// Round 4
// baseline (109.286 us; speedup 1.0000x reference)
//
#include <hip/hip_runtime.h>

// Batched Kalman filter, fully reduced:
//   B   = H @ phi            (8x16)      Cphi = C @ phi          (8x16)
//   Sc  = H diag(Q) H^T + diag(R) (8x8)  CQH  = C diag(Q) H^T    (8x8)
//   T   = P0 @ B^T           (16x8 per element, registers only)
//   S   = B @ T + Sc         (8x8 SPD)
//   y   = z - B @ x0
//   w   = S^-1 y             (lane-parallel GE, no pivoting)
//   out = Cphi @ (x0 + T w) + CQH @ w
// x_pred / x_new / P_pred are never formed. 8 threads per element (thread i
// owns rows i, i+8 of P0/T), 32 elements per 256-thread block. After two
// prologue barriers the per-element pipeline is barrier-free: S is built from
// register T rows via 8-wide shuffles; B@x0 and the output dot use 7-shfl
// reduce-scatters. LDS = constants only (~5 KB) -> occupancy is VGPR-bound.
//
// NOTE: plain __launch_bounds__(256); a min-waves hint (256,6) forced
// VGPR=40 and ~470 MB of scratch spill traffic in round 2. Don't.

#define QFMA(ACC, OFF, A, V) { ACC[(OFF)+0] += (A)*(V).x; ACC[(OFF)+1] += (A)*(V).y; ACC[(OFF)+2] += (A)*(V).z; ACC[(OFF)+3] += (A)*(V).w; }

__global__ __launch_bounds__(256) void kalman_fused4(
    const float* __restrict__ z,
    const float* __restrict__ x0,
    const float* __restrict__ P0,
    const float* __restrict__ phi,
    const float* __restrict__ Hm,
    const float* __restrict__ Cm,
    const float* __restrict__ Qd,
    const float* __restrict__ Rd,
    float* __restrict__ out,
    int bs)
{
    __shared__ __align__(16) float phiS[16 * 20]; // phi rows, stride 20
    __shared__ __align__(16) float HnS[8 * 20];   // H rows, stride 20
    __shared__ __align__(16) float CsS[8 * 20];   // C rows, stride 20
    __shared__ __align__(16) float BnS[8 * 20];   // B rows, stride 20
    __shared__ __align__(16) float BTS[16 * 8];   // BTS[k*8+m] = B[m][k]
    __shared__ __align__(16) float CPTS[16 * 8];  // CPTS[k*8+m] = Cphi[m][k]
    __shared__ __align__(16) float CQHS[8 * 8];   // CQH rows
    __shared__ __align__(16) float ScS[8 * 8];    // Sc rows
    __shared__            float QdS[16];
    __shared__            float RdS[8];

    const int tid = threadIdx.x;
    const int e = tid >> 3;   // element in block (0..31)
    const int i = tid & 7;    // lane in element (0..7)
    long b = (long)blockIdx.x * 32 + e;
    const bool valid = (b < (long)bs);
    if (!valid) b = (long)bs - 1;

    // ---- stage raw constants (coalesced) ----
    {
        const int r = tid >> 4, c = tid & 15;
        phiS[r * 20 + c] = phi[tid];
    }
    if (tid < 128) {
        const int m = tid >> 4, k = tid & 15;
        HnS[m * 20 + k] = Hm[tid];
        CsS[m * 20 + k] = Cm[tid];
    }
    if (tid < 16) QdS[tid] = Qd[tid];
    if (tid < 8)  RdS[tid] = Rd[tid];

    // per-element loads issued early (latency hidden under derive phase)
    const float x0a = x0[b * 16 + i];
    const float x0b = x0[b * 16 + 8 + i];
    float yv = z[b * 8 + i];
    float4 Pq[8];
    {
        const float4* P0v = reinterpret_cast<const float4*>(P0 + (size_t)b * 256);
#pragma unroll
        for (int q = 0; q < 4; ++q) {
            Pq[q]     = P0v[i * 4 + q];
            Pq[q + 4] = P0v[(i + 8) * 4 + q];
        }
    }
    __syncthreads();  // raw staged

    // ---- derived per-block matrices ----
    if (tid < 128) {
        const int m = tid >> 4, k = tid & 15;
        float bv = 0.f, cv = 0.f;
#pragma unroll
        for (int j = 0; j < 16; ++j) {
            const float pj = phiS[j * 20 + k];
            bv += HnS[m * 20 + j] * pj;
            cv += CsS[m * 20 + j] * pj;
        }
        BnS[m * 20 + k] = bv;
        BTS[k * 8 + m]  = bv;
        CPTS[k * 8 + m] = cv;
    }
    if (tid < 64) {
        const int i2 = tid >> 3, j2 = tid & 7;
        float sc = (i2 == j2) ? RdS[i2] : 0.f;
        float cq = 0.f;
#pragma unroll
        for (int k = 0; k < 16; ++k) {
            const float qh = QdS[k] * HnS[j2 * 20 + k];
            sc += HnS[i2 * 20 + k] * qh;
            cq += CsS[i2 * 20 + k] * qh;
        }
        ScS[i2 * 8 + j2]  = sc;
        CQHS[i2 * 8 + j2] = cq;
    }
    __syncthreads();  // derived staged — no more barriers below

    // ---- T rows i, i+8: T[r][m] = sum_k P0[r][k] * B[m][k] ----
    float t0[8], t1[8];
#pragma unroll
    for (int m = 0; m < 8; ++m) { t0[m] = 0.f; t1[m] = 0.f; }
#pragma unroll
    for (int q = 0; q < 4; ++q) {
        const float4 A = Pq[q], B4 = Pq[q + 4];
        const float a[4] = {A.x, A.y, A.z, A.w};
        const float c[4] = {B4.x, B4.y, B4.z, B4.w};
#pragma unroll
        for (int kk = 0; kk < 4; ++kk) {
            const int k = 4 * q + kk;
            const float4 b0 = *reinterpret_cast<const float4*>(&BTS[k * 8 + 0]);
            const float4 b1 = *reinterpret_cast<const float4*>(&BTS[k * 8 + 4]);
            QFMA(t0, 0, a[kk], b0) QFMA(t0, 4, a[kk], b1)
            QFMA(t1, 0, c[kk], b0) QFMA(t1, 4, c[kk], b1)
        }
    }

    // ---- y_i = z_i - (B @ x0)_i via partials + 7-shfl reduce-scatter ----
    {
        float yp[8];
        {
            const float4 u0 = *reinterpret_cast<const float4*>(&BTS[i * 8 + 0]);
            const float4 u1 = *reinterpret_cast<const float4*>(&BTS[i * 8 + 4]);
            const float4 v0 = *reinterpret_cast<const float4*>(&BTS[(i + 8) * 8 + 0]);
            const float4 v1 = *reinterpret_cast<const float4*>(&BTS[(i + 8) * 8 + 4]);
            yp[0] = u0.x*x0a + v0.x*x0b; yp[1] = u0.y*x0a + v0.y*x0b;
            yp[2] = u0.z*x0a + v0.z*x0b; yp[3] = u0.w*x0a + v0.w*x0b;
            yp[4] = u1.x*x0a + v1.x*x0b; yp[5] = u1.y*x0a + v1.y*x0b;
            yp[6] = u1.z*x0a + v1.z*x0b; yp[7] = u1.w*x0a + v1.w*x0b;
        }
        float v4[4];
#pragma unroll
        for (int j = 0; j < 4; ++j) {
            const float send = (i & 4) ? yp[j] : yp[j + 4];
            const float keep = (i & 4) ? yp[j + 4] : yp[j];
            v4[j] = keep + __shfl(send, i ^ 4, 8);
        }
        float v2[2];
#pragma unroll
        for (int j = 0; j < 2; ++j) {
            const float send = (i & 2) ? v4[j] : v4[j + 2];
            const float keep = (i & 2) ? v4[j + 2] : v4[j];
            v2[j] = keep + __shfl(send, i ^ 2, 8);
        }
        {
            const float send = (i & 1) ? v2[0] : v2[1];
            const float keep = (i & 1) ? v2[1] : v2[0];
            yv -= keep + __shfl(send, i ^ 1, 8);
        }
    }

    // ---- S row i = Sc[i,:] + sum_k B[i][k] * T[k][:] (T rows via shfl) ----
    float br[16];
#pragma unroll
    for (int q = 0; q < 4; ++q) {
        const float4 A = *reinterpret_cast<const float4*>(&BnS[i * 20 + 4 * q]);
        br[4*q+0] = A.x; br[4*q+1] = A.y; br[4*q+2] = A.z; br[4*q+3] = A.w;
    }
    float s[8];
    {
        const float4 c0 = *reinterpret_cast<const float4*>(&ScS[i * 8 + 0]);
        const float4 c1 = *reinterpret_cast<const float4*>(&ScS[i * 8 + 4]);
        s[0]=c0.x; s[1]=c0.y; s[2]=c0.z; s[3]=c0.w; s[4]=c1.x; s[5]=c1.y; s[6]=c1.z; s[7]=c1.w;
    }
#pragma unroll
    for (int k = 0; k < 8; ++k) {
        const float bk = br[k];
#pragma unroll
        for (int n = 0; n < 8; ++n) s[n] += bk * __shfl(t0[n], k, 8);
    }
#pragma unroll
    for (int k = 0; k < 8; ++k) {
        const float bk = br[k + 8];
#pragma unroll
        for (int n = 0; n < 8; ++n) s[n] += bk * __shfl(t1[n], k, 8);
    }

    // ---- solve S w = y : lane-parallel GE (S SPD, no pivoting) ----
#pragma unroll
    for (int k = 0; k < 7; ++k) {
        float pr[8];
#pragma unroll
        for (int j = 0; j < 8; ++j) pr[j] = __shfl(s[j], k, 8);
        const float py = __shfl(yv, k, 8);
        if (i > k) {
            const float f = s[k] / pr[k];
#pragma unroll
            for (int j = 0; j < 8; ++j) s[j] -= f * pr[j];
            yv -= f * py;
        }
    }
    float w[8];
#pragma unroll
    for (int k = 7; k >= 0; --k) {
        const float num = __shfl(yv, k, 8);
        const float den = __shfl(s[k], k, 8);
        const float wk = num / den;
        w[k] = wk;
        if (i < k) yv -= s[k] * wk;
    }

    // ---- t-hat rows (registers): th = T[r,:] @ w ----
    float th0 = 0.f, th1 = 0.f;
#pragma unroll
    for (int m = 0; m < 8; ++m) { th0 += t0[m] * w[m]; th1 += t1[m] * w[m]; }
    const float u0v = x0a + th0;   // (x0 + T w) rows i, i+8
    const float u1v = x0b + th1;

    // ---- out[i] = Cphi[i,:] @ (x0 + T w) + CQH[i,:] @ w ----
    float op[8];
    {
        const float4 a0 = *reinterpret_cast<const float4*>(&CPTS[i * 8 + 0]);
        const float4 a1 = *reinterpret_cast<const float4*>(&CPTS[i * 8 + 4]);
        const float4 b0 = *reinterpret_cast<const float4*>(&CPTS[(i + 8) * 8 + 0]);
        const float4 b1 = *reinterpret_cast<const float4*>(&CPTS[(i + 8) * 8 + 4]);
        op[0] = a0.x*u0v + b0.x*u1v; op[1] = a0.y*u0v + b0.y*u1v;
        op[2] = a0.z*u0v + b0.z*u1v; op[3] = a0.w*u0v + b0.w*u1v;
        op[4] = a1.x*u0v + b1.x*u1v; op[5] = a1.y*u0v + b1.y*u1v;
        op[6] = a1.z*u0v + b1.z*u1v; op[7] = a1.w*u0v + b1.w*u1v;
    }
    float oc;
    {
        float v4[4];
#pragma unroll
        for (int j = 0; j < 4; ++j) {
            const float send = (i & 4) ? op[j] : op[j + 4];
            const float keep = (i & 4) ? op[j + 4] : op[j];
            v4[j] = keep + __shfl(send, i ^ 4, 8);
        }
        float v2[2];
#pragma unroll
        for (int j = 0; j < 2; ++j) {
            const float send = (i & 2) ? v4[j] : v4[j + 2];
            const float keep = (i & 2) ? v4[j + 2] : v4[j];
            v2[j] = keep + __shfl(send, i ^ 2, 8);
        }
        const float send = (i & 1) ? v2[0] : v2[1];
        const float keep = (i & 1) ? v2[1] : v2[0];
        oc = keep + __shfl(send, i ^ 1, 8);
    }
    {
        const float4 q0 = *reinterpret_cast<const float4*>(&CQHS[i * 8 + 0]);
        const float4 q1 = *reinterpret_cast<const float4*>(&CQHS[i * 8 + 4]);
        oc += q0.x*w[0] + q0.y*w[1] + q0.z*w[2] + q0.w*w[3]
            + q1.x*w[4] + q1.y*w[5] + q1.z*w[6] + q1.w*w[7];
    }
    if (valid) out[b * 8 + i] = oc;
}

extern "C" void kernel_launch(void* const* d_in, const int* in_sizes, int n_in,
                              void* d_out, int out_size, void* d_ws, size_t ws_size,
                              hipStream_t stream)
{
    const float* z   = (const float*)d_in[0];
    const float* x0  = (const float*)d_in[1];
    const float* P0  = (const float*)d_in[2];
    const float* phi = (const float*)d_in[3];
    const float* H   = (const float*)d_in[4];
    const float* C   = (const float*)d_in[5];
    const float* Qd  = (const float*)d_in[6];
    const float* Rd  = (const float*)d_in[7];
    float* out = (float*)d_out;

    const int bs = in_sizes[0] / 8;          // z is [bs, 8]
    const int blocks = (bs + 31) / 32;       // 32 elements per block
    hipLaunchKernelGGL(kalman_fused4, dim3(blocks), dim3(256), 0, stream,
                       z, x0, P0, phi, H, C, Qd, Rd, out, bs);
}

// Round 5
// 80.043 us; speedup vs baseline: 1.3654x; 1.3654x over previous
//
#include <hip/hip_runtime.h>

// Batched Kalman filter, fully reduced:
//   B    = H @ phi                  (8x16)   Cphi = C @ phi      (8x16)
//   Sc   = H diag(Q) H^T + diag(R)  (8x8)    CQH  = C diag(Q) H^T (8x8)
//   T    = P0 @ B^T                 (16x8 per element)
//   S    = B @ T + Sc               (8x8 SPD)
//   y    = z - B @ x0
//   w    = S^-1 y                   (lane-parallel GE, no pivoting)
//   out  = Cphi @ (x0 + T w) + CQH @ w
// x_pred / x_new / P_pred never formed. 8 threads per element (thread i owns
// rows i, i+8), 32 elements per 256-thread block.
//
// Structure notes (hard-won):
//  - plain __launch_bounds__(256): a min-waves hint forced VGPR=40 and
//    ~470 MB of scratch spill traffic in round 2. Never again.
//  - Cross-lane matrix transport (T) goes through LDS as b128 round-trips;
//    round 4 proved per-scalar shuffles for this are ~4x more DS-pipe issue
//    and cost +22 us. Shuffles only for the 8x8 solve and 16-wide gathers.
//  - NO barrier around the T round-trip: producer and consumer are the same
//    8 lanes of one wave64 (8 | 64); intra-wave DS ops are program-ordered.
//    Post-derive phase is barrier-free so waves drift and hide P0 latency.

#define QFMA(ACC, OFF, A, V) { ACC[(OFF)+0] += (A)*(V).x; ACC[(OFF)+1] += (A)*(V).y; ACC[(OFF)+2] += (A)*(V).z; ACC[(OFF)+3] += (A)*(V).w; }
#define TS 132  // per-element float stride of T buffer (4*33: odd quad -> bijective bank spread)

__global__ __launch_bounds__(256) void kalman_fused5(
    const float* __restrict__ z,
    const float* __restrict__ x0,
    const float* __restrict__ P0,
    const float* __restrict__ phi,
    const float* __restrict__ Hm,
    const float* __restrict__ Cm,
    const float* __restrict__ Qd,
    const float* __restrict__ Rd,
    float* __restrict__ out,
    int bs)
{
    __shared__ __align__(16) float phiS[16 * 20]; // phi rows, stride 20 (prologue only)
    __shared__ __align__(16) float HnS[8 * 20];   // H rows, stride 20 (prologue only)
    __shared__ __align__(16) float CsS[8 * 20];   // C rows, stride 20 (prologue only)
    __shared__ __align__(16) float BnS[8 * 20];   // B rows, stride 20
    __shared__ __align__(16) float BTS[16 * 8];   // BTS[k*8+m] = B[m][k] (broadcast reads)
    __shared__ __align__(16) float CpS[8 * 20];   // Cphi rows, stride 20
    __shared__ __align__(16) float CQHS[8 * 8];   // CQH rows
    __shared__ __align__(16) float ScS[8 * 8];    // Sc rows
    __shared__            float QdS[16];
    __shared__            float RdS[8];
    __shared__ __align__(16) float x0S[32 * 20];  // per-element x0, stride 20
    __shared__ __align__(16) float Tb[32 * TS];   // per-element T (16 rows x 8)

    const int tid = threadIdx.x;
    const int e = tid >> 3;   // element in block (0..31)
    const int i = tid & 7;    // lane in element (0..7)
    long b = (long)blockIdx.x * 32 + e;
    const bool valid = (b < (long)bs);
    if (!valid) b = (long)bs - 1;

    // ---- stage raw constants (coalesced) ----
    {
        const int r = tid >> 4, c = tid & 15;
        phiS[r * 20 + c] = phi[tid];
    }
    if (tid < 128) {
        const int m = tid >> 4, k = tid & 15;
        HnS[m * 20 + k] = Hm[tid];
        CsS[m * 20 + k] = Cm[tid];
    }
    if (tid < 16) QdS[tid] = Qd[tid];
    if (tid < 8)  RdS[tid] = Rd[tid];

    // per-element loads issued early (latency hidden under derive phase)
    const float x0a = x0[b * 16 + i];
    const float x0b = x0[b * 16 + 8 + i];
    x0S[e * 20 + i]     = x0a;
    x0S[e * 20 + i + 8] = x0b;
    float yv = z[b * 8 + i];
    float4 Pq[8];
    {
        const float4* P0v = reinterpret_cast<const float4*>(P0 + (size_t)b * 256);
#pragma unroll
        for (int q = 0; q < 4; ++q) {
            Pq[q]     = P0v[i * 4 + q];
            Pq[q + 4] = P0v[(i + 8) * 4 + q];
        }
    }
    __syncthreads();  // raw constants staged

    // ---- derived per-block matrices ----
    if (tid < 128) {
        const int m = tid >> 4, k = tid & 15;
        float bv = 0.f, cv = 0.f;
#pragma unroll
        for (int j = 0; j < 16; ++j) {
            const float pj = phiS[j * 20 + k];
            bv += HnS[m * 20 + j] * pj;
            cv += CsS[m * 20 + j] * pj;
        }
        BnS[m * 20 + k] = bv;
        BTS[k * 8 + m]  = bv;
        CpS[m * 20 + k] = cv;
    }
    if (tid < 64) {
        const int i2 = tid >> 3, j2 = tid & 7;
        float sc = (i2 == j2) ? RdS[i2] : 0.f;
        float cq = 0.f;
#pragma unroll
        for (int k = 0; k < 16; ++k) {
            const float qh = QdS[k] * HnS[j2 * 20 + k];
            sc += HnS[i2 * 20 + k] * qh;
            cq += CsS[i2 * 20 + k] * qh;
        }
        ScS[i2 * 8 + j2]  = sc;
        CQHS[i2 * 8 + j2] = cq;
    }
    __syncthreads();  // derived staged — NO barriers below this point

    // ---- T rows i, i+8: T[r][m] = sum_k P0[r][k] * B[m][k] ----
    float t0[8], t1[8];
#pragma unroll
    for (int m = 0; m < 8; ++m) { t0[m] = 0.f; t1[m] = 0.f; }
#pragma unroll
    for (int q = 0; q < 4; ++q) {
        const float4 A = Pq[q], B4 = Pq[q + 4];
        const float a[4] = {A.x, A.y, A.z, A.w};
        const float c[4] = {B4.x, B4.y, B4.z, B4.w};
#pragma unroll
        for (int kk = 0; kk < 4; ++kk) {
            const int k = 4 * q + kk;
            const float4 b0 = *reinterpret_cast<const float4*>(&BTS[k * 8 + 0]);
            const float4 b1 = *reinterpret_cast<const float4*>(&BTS[k * 8 + 4]);
            QFMA(t0, 0, a[kk], b0) QFMA(t0, 4, a[kk], b1)
            QFMA(t1, 0, c[kk], b0) QFMA(t1, 4, c[kk], b1)
        }
    }
    // stage T (intra-wave round-trip; producer==consumer wave, no barrier)
    *reinterpret_cast<float4*>(&Tb[e * TS + i * 8 + 0]) = make_float4(t0[0], t0[1], t0[2], t0[3]);
    *reinterpret_cast<float4*>(&Tb[e * TS + i * 8 + 4]) = make_float4(t0[4], t0[5], t0[6], t0[7]);
    *reinterpret_cast<float4*>(&Tb[e * TS + (i + 8) * 8 + 0]) = make_float4(t1[0], t1[1], t1[2], t1[3]);
    *reinterpret_cast<float4*>(&Tb[e * TS + (i + 8) * 8 + 4]) = make_float4(t1[4], t1[5], t1[6], t1[7]);

    // ---- B row i -> regs ----
    float br[16];
#pragma unroll
    for (int q = 0; q < 4; ++q) {
        const float4 A = *reinterpret_cast<const float4*>(&BnS[i * 20 + 4 * q]);
        br[4*q+0] = A.x; br[4*q+1] = A.y; br[4*q+2] = A.z; br[4*q+3] = A.w;
    }

    // ---- S row i = Sc[i,:] + B[i,:] @ T ----
    float s[8];
    {
        const float4 c0 = *reinterpret_cast<const float4*>(&ScS[i * 8 + 0]);
        const float4 c1 = *reinterpret_cast<const float4*>(&ScS[i * 8 + 4]);
        s[0]=c0.x; s[1]=c0.y; s[2]=c0.z; s[3]=c0.w; s[4]=c1.x; s[5]=c1.y; s[6]=c1.z; s[7]=c1.w;
    }
#pragma unroll
    for (int j = 0; j < 16; ++j) {
        const float4 ta = *reinterpret_cast<const float4*>(&Tb[e * TS + j * 8 + 0]);
        const float4 tb = *reinterpret_cast<const float4*>(&Tb[e * TS + j * 8 + 4]);
        const float bij = br[j];
        QFMA(s, 0, bij, ta) QFMA(s, 4, bij, tb)
    }

    // ---- y_i = z_i - B[i,:] @ x0 ----
#pragma unroll
    for (int q = 0; q < 4; ++q) {
        const float4 X = *reinterpret_cast<const float4*>(&x0S[e * 20 + 4 * q]);
        yv -= br[4*q+0]*X.x + br[4*q+1]*X.y + br[4*q+2]*X.z + br[4*q+3]*X.w;
    }

    // ---- solve S w = y : lane-parallel GE (S SPD, no pivoting) ----
#pragma unroll
    for (int k = 0; k < 7; ++k) {
        float pr[8];
#pragma unroll
        for (int j = k; j < 8; ++j) pr[j] = __shfl(s[j], k, 8);
        const float py = __shfl(yv, k, 8);
        if (i > k) {
            const float f = s[k] / pr[k];
#pragma unroll
            for (int j = k; j < 8; ++j) s[j] -= f * pr[j];
            yv -= f * py;
        }
    }
    float w[8];
#pragma unroll
    for (int k = 7; k >= 0; --k) {
        const float num = __shfl(yv, k, 8);
        const float den = __shfl(s[k], k, 8);
        const float wk = num / den;
        w[k] = wk;
        if (i < k) yv -= s[k] * wk;
    }

    // ---- u rows = x0 + T w (registers) ----
    float th0 = 0.f, th1 = 0.f;
#pragma unroll
    for (int m = 0; m < 8; ++m) { th0 += t0[m] * w[m]; th1 += t1[m] * w[m]; }
    const float u0v = x0a + th0;
    const float u1v = x0b + th1;

    // ---- gather full u via shuffles ----
    float uv[16];
#pragma unroll
    for (int j = 0; j < 8; ++j) {
        uv[j]     = __shfl(u0v, j, 8);
        uv[j + 8] = __shfl(u1v, j, 8);
    }

    // ---- out[b][i] = Cphi[i,:] @ u + CQH[i,:] @ w ----
    float oc = 0.f;
#pragma unroll
    for (int q = 0; q < 4; ++q) {
        const float4 A = *reinterpret_cast<const float4*>(&CpS[i * 20 + 4 * q]);
        oc += A.x*uv[4*q+0] + A.y*uv[4*q+1] + A.z*uv[4*q+2] + A.w*uv[4*q+3];
    }
    {
        const float4 q0 = *reinterpret_cast<const float4*>(&CQHS[i * 8 + 0]);
        const float4 q1 = *reinterpret_cast<const float4*>(&CQHS[i * 8 + 4]);
        oc += q0.x*w[0] + q0.y*w[1] + q0.z*w[2] + q0.w*w[3]
            + q1.x*w[4] + q1.y*w[5] + q1.z*w[6] + q1.w*w[7];
    }
    if (valid) out[b * 8 + i] = oc;
}

extern "C" void kernel_launch(void* const* d_in, const int* in_sizes, int n_in,
                              void* d_out, int out_size, void* d_ws, size_t ws_size,
                              hipStream_t stream)
{
    const float* z   = (const float*)d_in[0];
    const float* x0  = (const float*)d_in[1];
    const float* P0  = (const float*)d_in[2];
    const float* phi = (const float*)d_in[3];
    const float* H   = (const float*)d_in[4];
    const float* C   = (const float*)d_in[5];
    const float* Qd  = (const float*)d_in[6];
    const float* Rd  = (const float*)d_in[7];
    float* out = (float*)d_out;

    const int bs = in_sizes[0] / 8;          // z is [bs, 8]
    const int blocks = (bs + 31) / 32;       // 32 elements per block
    hipLaunchKernelGGL(kalman_fused5, dim3(blocks), dim3(256), 0, stream,
                       z, x0, P0, phi, H, C, Qd, Rd, out, bs);
}